// Round 1
// baseline (114.183 us; speedup 1.0000x reference)
//
#include <hip/hip_runtime.h>

static constexpr int DATA_BITS  = 48;
static constexpr int SHIFT_BITS = 6;

__global__ __launch_bounds__(256) void barrel48_kernel(
    const float* __restrict__ X, const float* __restrict__ shift,
    float* __restrict__ out, int B)
{
    int idx = blockIdx.x * 256 + threadIdx.x;
    if (idx >= B) return;

    // ---- load the 48-bit row (12 x float4, 16B-aligned: 192B row stride) ----
    const float4* xr = reinterpret_cast<const float4*>(X + (size_t)idx * DATA_BITS);
    float4 f[12];
    #pragma unroll
    for (int k = 0; k < 12; ++k) f[k] = xr[k];

    // ---- pack MSB-first bits via exact float Horner (1 fmac per bit) ----
    // values stay < 2^24 so fp32 accumulation is exact
    float hi_f = 0.0f, lo_f = 0.0f;
    #pragma unroll
    for (int k = 0; k < 6; ++k) {          // bits 47..24 (MSB side) -> hi
        hi_f = fmaf(hi_f, 2.0f, f[k].x);
        hi_f = fmaf(hi_f, 2.0f, f[k].y);
        hi_f = fmaf(hi_f, 2.0f, f[k].z);
        hi_f = fmaf(hi_f, 2.0f, f[k].w);
    }
    #pragma unroll
    for (int k = 6; k < 12; ++k) {         // bits 23..0 -> lo
        lo_f = fmaf(lo_f, 2.0f, f[k].x);
        lo_f = fmaf(lo_f, 2.0f, f[k].y);
        lo_f = fmaf(lo_f, 2.0f, f[k].z);
        lo_f = fmaf(lo_f, 2.0f, f[k].w);
    }
    unsigned long long v =
        ((unsigned long long)(unsigned)hi_f << 24) | (unsigned long long)(unsigned)lo_f;

    // ---- shift amount: 6 MSB-first bits -> 0..63 (Horner again) ----
    const float2* sr = reinterpret_cast<const float2*>(shift + (size_t)idx * SHIFT_BITS);
    float2 s0 = sr[0], s1 = sr[1], s2 = sr[2];
    float sf = s0.x;
    sf = fmaf(sf, 2.0f, s0.y);
    sf = fmaf(sf, 2.0f, s1.x);
    sf = fmaf(sf, 2.0f, s1.y);
    sf = fmaf(sf, 2.0f, s2.x);
    sf = fmaf(sf, 2.0f, s2.y);
    unsigned s = (unsigned)sf;             // 0..63

    // ---- the actual barrel shift + sticky ----
    unsigned long long shifted = v >> s;                       // s <= 63, well-defined
    unsigned long long dropped = v & ((1ull << s) - 1ull);     // bits shifted out
    float sticky = dropped ? 1.0f : 0.0f;

    // ---- unpack to 48 floats, MSB first; write 12 x float4 ----
    unsigned lo32 = (unsigned)shifted;             // bits 0..31
    unsigned hi32 = (unsigned)(shifted >> 32);     // bits 32..47
    float4* orow = reinterpret_cast<float4*>(out + (size_t)idx * DATA_BITS);
    #pragma unroll
    for (int k = 0; k < 12; ++k) {
        float4 o;
        float* op = &o.x;
        #pragma unroll
        for (int t = 0; t < 4; ++t) {
            int j = k * 4 + t;                     // output position, MSB first
            unsigned bit = (j < 16) ? ((hi32 >> (15 - j)) & 1u)
                                    : ((lo32 >> (47 - j)) & 1u);
            op[t] = (float)bit;
        }
        orow[k] = o;
    }

    // ---- sticky goes after the B*48 data block (tuple concat order) ----
    out[(size_t)B * DATA_BITS + idx] = sticky;
}

extern "C" void kernel_launch(void* const* d_in, const int* in_sizes, int n_in,
                              void* d_out, int out_size, void* d_ws, size_t ws_size,
                              hipStream_t stream)
{
    const float* X     = (const float*)d_in[0];
    const float* shift = (const float*)d_in[1];
    float* out         = (float*)d_out;
    int B = in_sizes[0] / DATA_BITS;
    int blocks = (B + 255) / 256;
    barrel48_kernel<<<blocks, 256, 0, stream>>>(X, shift, out, B);
}

// Round 2
// 86.649 us; speedup vs baseline: 1.3178x; 1.3178x over previous
//
#include <hip/hip_runtime.h>

static constexpr int DATA_BITS  = 48;
static constexpr int SHIFT_BITS = 6;
static constexpr int THREADS    = 256;   // threads per block == rows per block
static constexpr int ROWS       = 256;
static constexpr int ROW_DW     = 13;    // LDS data row stride in dwords (52 B, gcd(13,32)=1)
static constexpr int RES_DW     = 3;     // LDS result row stride in dwords (12 B)

__global__ __launch_bounds__(256) void barrel48_kernel(
    const float* __restrict__ X, const float* __restrict__ shift,
    float* __restrict__ out, int B)
{
    __shared__ unsigned lds_data[ROWS * ROW_DW];  // 13312 B: bits-as-bytes, 48B/row + 4B pad
    __shared__ unsigned lds_res [ROWS * RES_DW];  // 3072 B: packed 48-bit results

    const unsigned tid = threadIdx.x;
    const size_t rowbase = (size_t)blockIdx.x * ROWS;

    // ---------- phase 1: coalesced load of X tile -> bytes in LDS ----------
    // tile = ROWS*48 floats = 3072 float4; instruction k: lanes read contiguous.
    const float4* xb = reinterpret_cast<const float4*>(X + rowbase * DATA_BITS);
    #pragma unroll
    for (int k = 0; k < 12; ++k) {
        unsigned f4 = (unsigned)(k * THREADS) + tid;       // 0..3071, contiguous per instr
        float4 f = xb[f4];
        unsigned r = f4 / 12u;                              // row in tile
        unsigned n = f4 % 12u;                              // which float4 of the row
        // pack 4 exact-0/1 floats into 4 bytes (byte0 = first/most-significant float)
        unsigned pk = (unsigned)f.x | ((unsigned)f.y << 8) |
                      ((unsigned)f.z << 16) | ((unsigned)f.w << 24);
        lds_data[r * ROW_DW + n] = pk;
    }
    __syncthreads();

    // ---------- phase 2: per-thread row pack + shift + sticky ----------
    unsigned hi16 = 0, lo32 = 0;
    #pragma unroll
    for (int n = 0; n < 12; ++n) {
        unsigned d = lds_data[tid * ROW_DW + n];            // bank = (13*tid+n)%32 -> 2-way max
        // gather the 4 byte-bits into a nibble, byte0 -> bit3 (MSB-first)
        unsigned q = ((d * 0x08040201u) >> 24) & 0xFu;
        if (n < 4) hi16 = (hi16 << 4) | q;                  // v bits 47..32
        else       lo32 = (lo32 << 4) | q;                  // v bits 31..0
    }
    unsigned long long v = ((unsigned long long)hi16 << 32) | (unsigned long long)lo32;

    // shift amount: 6 MSB-first bits, Horner (exact in fp32)
    const float2* sp = reinterpret_cast<const float2*>(shift + (rowbase + tid) * SHIFT_BITS);
    float2 s0 = sp[0], s1 = sp[1], s2 = sp[2];
    float sf = s0.x;
    sf = fmaf(sf, 2.0f, s0.y);
    sf = fmaf(sf, 2.0f, s1.x);
    sf = fmaf(sf, 2.0f, s1.y);
    sf = fmaf(sf, 2.0f, s2.x);
    sf = fmaf(sf, 2.0f, s2.y);
    unsigned s = (unsigned)sf;                              // 0..63

    unsigned long long shifted = v >> s;
    unsigned long long dropped = v & ((1ull << s) - 1ull);  // union of all dropped bits

    // sticky: scalar, coalesced across lanes
    out[(size_t)B * DATA_BITS + rowbase + tid] = dropped ? 1.0f : 0.0f;

    lds_res[tid * RES_DW + 0] = (unsigned)shifted;          // bits 31..0
    lds_res[tid * RES_DW + 1] = (unsigned)(shifted >> 32);  // bits 47..32
    __syncthreads();

    // ---------- phase 3: coalesced expand + store ----------
    float4* ob = reinterpret_cast<float4*>(out + rowbase * DATA_BITS);
    #pragma unroll
    for (int k = 0; k < 12; ++k) {
        unsigned f4 = (unsigned)(k * THREADS) + tid;
        unsigned r = f4 / 12u;
        unsigned n = f4 % 12u;
        // nibble n covers output floats 4n..4n+3 = v bits 47-4n..44-4n
        unsigned d = lds_res[r * RES_DW + (n < 4u ? 1u : 0u)];  // same-addr -> broadcast
        unsigned nib = (d >> ((44u - 4u * n) & 31u)) & 0xFu;
        float4 o;
        o.x = (float)((nib >> 3) & 1u);
        o.y = (float)((nib >> 2) & 1u);
        o.z = (float)((nib >> 1) & 1u);
        o.w = (float)( nib       & 1u);
        ob[f4] = o;                                          // contiguous per instr
    }
}

extern "C" void kernel_launch(void* const* d_in, const int* in_sizes, int n_in,
                              void* d_out, int out_size, void* d_ws, size_t ws_size,
                              hipStream_t stream)
{
    const float* X     = (const float*)d_in[0];
    const float* shift = (const float*)d_in[1];
    float* out         = (float*)d_out;
    int B = in_sizes[0] / DATA_BITS;
    int blocks = (B + ROWS - 1) / ROWS;
    barrel48_kernel<<<blocks, THREADS, 0, stream>>>(X, shift, out, B);
}

// Round 4
// 62.009 us; speedup vs baseline: 1.8414x; 1.3973x over previous
//
#include <hip/hip_runtime.h>

static constexpr int DATA_BITS  = 48;
static constexpr int SHIFT_BITS = 6;
static constexpr int THREADS    = 256;   // 4 waves; each wave owns 64 rows
static constexpr int ROWS       = 256;
static constexpr int ROW_DW     = 13;    // LDS data row stride in dwords (52 B, gcd(13,32)=1)
static constexpr int RES_DW     = 3;     // LDS result row stride in dwords (12 B)

typedef float  vf4 __attribute__((ext_vector_type(4)));
typedef float  vf2 __attribute__((ext_vector_type(2)));

__global__ __launch_bounds__(256) void barrel48_kernel(
    const float* __restrict__ X, const float* __restrict__ shift,
    float* __restrict__ out, int B)
{
    __shared__ unsigned lds_data[ROWS * ROW_DW];  // 13312 B, bits-as-bytes
    __shared__ unsigned lds_res [ROWS * RES_DW];  // 3072 B, packed 48-bit results

    const unsigned tid  = threadIdx.x;
    const unsigned wv   = tid >> 6;               // wave id 0..3
    const unsigned lane = tid & 63;
    const size_t rowbase = (size_t)blockIdx.x * ROWS;

    // ---------- phase 1 (wave-local): coalesced load -> bytes in LDS ----------
    // wave w owns rows [w*64, w*64+64) == vf4 flat indices [w*768, w*768+768)
    const vf4* xb = reinterpret_cast<const vf4*>(X + rowbase * DATA_BITS);
    #pragma unroll
    for (int j = 0; j < 12; ++j) {
        unsigned f4 = wv * 768u + (unsigned)j * 64u + lane;  // contiguous 1KB per instr
        vf4 f = xb[f4];
        unsigned r = f4 / 12u;                               // row in tile (wave-local)
        unsigned n = f4 % 12u;
        unsigned pk = (unsigned)f.x | ((unsigned)f.y << 8) |
                      ((unsigned)f.z << 16) | ((unsigned)f.w << 24);
        lds_data[r * ROW_DW + n] = pk;
    }
    __builtin_amdgcn_wave_barrier();   // scheduling fence only; wave-synchronous LDS

    // ---------- phase 2 (wave-local): row pack + shift + sticky ----------
    unsigned hi16 = 0, lo32 = 0;
    #pragma unroll
    for (int n = 0; n < 12; ++n) {
        unsigned d = lds_data[tid * ROW_DW + n];             // own wave's slice
        unsigned q = ((d * 0x08040201u) >> 24) & 0xFu;       // 4 byte-bits -> nibble, MSB first
        if (n < 4) hi16 = (hi16 << 4) | q;                   // v bits 47..32
        else       lo32 = (lo32 << 4) | q;                   // v bits 31..0
    }
    unsigned long long v = ((unsigned long long)hi16 << 32) | (unsigned long long)lo32;

    const vf2* sp = reinterpret_cast<const vf2*>(shift + (rowbase + tid) * SHIFT_BITS);
    vf2 s0 = sp[0], s1 = sp[1], s2 = sp[2];
    float sf = s0.x;
    sf = fmaf(sf, 2.0f, s0.y);
    sf = fmaf(sf, 2.0f, s1.x);
    sf = fmaf(sf, 2.0f, s1.y);
    sf = fmaf(sf, 2.0f, s2.x);
    sf = fmaf(sf, 2.0f, s2.y);
    unsigned s = (unsigned)sf;                               // 0..63

    unsigned long long shifted = v >> s;
    unsigned long long dropped = v & ((1ull << s) - 1ull);

    __builtin_nontemporal_store(dropped ? 1.0f : 0.0f,
                                out + (size_t)B * DATA_BITS + rowbase + tid);

    lds_res[tid * RES_DW + 0] = (unsigned)shifted;           // bits 31..0
    lds_res[tid * RES_DW + 1] = (unsigned)(shifted >> 32);   // bits 47..32
    __builtin_amdgcn_wave_barrier();

    // ---------- phase 3 (wave-local): expand + nontemporal coalesced store ----------
    vf4* ob = reinterpret_cast<vf4*>(out + rowbase * DATA_BITS);
    #pragma unroll
    for (int j = 0; j < 12; ++j) {
        unsigned f4 = wv * 768u + (unsigned)j * 64u + lane;
        unsigned r = f4 / 12u;                               // wave-local row
        unsigned n = f4 % 12u;
        unsigned d = lds_res[r * RES_DW + (n < 4u ? 1u : 0u)];
        unsigned nib = (d >> ((44u - 4u * n) & 31u)) & 0xFu;
        vf4 o;
        o.x = (float)((nib >> 3) & 1u);
        o.y = (float)((nib >> 2) & 1u);
        o.z = (float)((nib >> 1) & 1u);
        o.w = (float)( nib       & 1u);
        __builtin_nontemporal_store(o, &ob[f4]);             // contiguous 1KB per instr
    }
}

extern "C" void kernel_launch(void* const* d_in, const int* in_sizes, int n_in,
                              void* d_out, int out_size, void* d_ws, size_t ws_size,
                              hipStream_t stream)
{
    const float* X     = (const float*)d_in[0];
    const float* shift = (const float*)d_in[1];
    float* out         = (float*)d_out;
    int B = in_sizes[0] / DATA_BITS;
    int blocks = (B + ROWS - 1) / ROWS;
    barrel48_kernel<<<blocks, THREADS, 0, stream>>>(X, shift, out, B);
}